// Round 1
// baseline (3523.164 us; speedup 1.0000x reference)
//
#include <hip/hip_runtime.h>

// Problem constants (fixed by the reference)
constexpr int Bc = 32, Sc = 1024, Hc = 256, Pc = 96, Lc = 200, Oc = 200, Ec = 64;
constexpr int Mtot = Bc * Sc;   // 32768 rows for all row-major GEMMs
constexpr float DT = 0.25f;     // 1/N_EULER
constexpr int QT = 8;           // q-rows per attention block

enum { MODE_ENC = 0, MODE_TANH = 1, MODE_EULER = 2, MODE_QKV = 3, MODE_OUT = 4 };

// ---------------------------------------------------------------------------
// eco_vec[b,h] = eco_data[b,:] @ W_eco[:,h] + b_eco[h]
// ---------------------------------------------------------------------------
__global__ __launch_bounds__(256) void eco_kernel(
    const float* __restrict__ eco_data, const float* __restrict__ W_eco,
    const float* __restrict__ b_eco, float* __restrict__ eco_vec)
{
    const int b = blockIdx.x, h = threadIdx.x;
    float acc = b_eco[h];
    #pragma unroll
    for (int e = 0; e < Ec; e++)
        acc = fmaf(eco_data[b * Ec + e], W_eco[(size_t)e * Hc + h], acc);
    eco_vec[(size_t)b * Hc + h] = acc;
}

// ---------------------------------------------------------------------------
// Generic 64x64-tile fp32 GEMM with fused epilogues.
// C[M,N] = epilogue( A[M,K] @ W[K,N] + bias[N] )
//   MODE_ENC:   C = tanh(.. + timev[m]*wt[n])
//   MODE_TANH:  C = tanh(..)
//   MODE_EULER: C = C + DT * (..)
//   MODE_QKV:   C = (.. + eco[b,n]) * mask(tran[m,255])
//   MODE_OUT:   C = ..
// ---------------------------------------------------------------------------
template <int MODE>
__global__ __launch_bounds__(256) void gemm_ep(
    const float* __restrict__ A, const float* __restrict__ W,
    const float* __restrict__ bias, float* __restrict__ C,
    int M, int N, int K,
    const float* __restrict__ timev, const float* __restrict__ wt,
    const float* __restrict__ eco, const float* __restrict__ trandat)
{
    __shared__ float As[16][68];   // [k][m], stride 68 floats keeps 16B alignment
    __shared__ float Bs[16][68];   // [k][n]
    const int tid = threadIdx.x;
    const int tx = tid & 15, ty = tid >> 4;
    const int m0 = blockIdx.y * 64;
    const int n0 = blockIdx.x * 64;

    float acc[4][4] = {};

    for (int k0 = 0; k0 < K; k0 += 16) {
        // A tile: 64 rows x 16 k  (lane-major over k for 64B segments)
        #pragma unroll
        for (int i = 0; i < 4; i++) {
            int e = i * 256 + tid;
            int m = e >> 4, kk = e & 15;
            float v = 0.f;
            if (k0 + kk < K) v = A[(size_t)(m0 + m) * K + (k0 + kk)];
            As[kk][m] = v;
        }
        // B tile: 16 k x 64 n (coalesced over n)
        #pragma unroll
        for (int i = 0; i < 4; i++) {
            int e = i * 256 + tid;
            int n = e & 63, kk = e >> 6;
            float v = 0.f;
            if ((k0 + kk) < K && (n0 + n) < N) v = W[(size_t)(k0 + kk) * N + (n0 + n)];
            Bs[kk][n] = v;
        }
        __syncthreads();
        #pragma unroll
        for (int kk = 0; kk < 16; kk++) {
            const float4 av = *(const float4*)&As[kk][ty * 4];
            const float4 bv = *(const float4*)&Bs[kk][tx * 4];
            const float a[4] = {av.x, av.y, av.z, av.w};
            const float b[4] = {bv.x, bv.y, bv.z, bv.w};
            #pragma unroll
            for (int i = 0; i < 4; i++)
                #pragma unroll
                for (int j = 0; j < 4; j++)
                    acc[i][j] = fmaf(a[i], b[j], acc[i][j]);
        }
        __syncthreads();
    }

    #pragma unroll
    for (int i = 0; i < 4; i++) {
        const int m = m0 + ty * 4 + i;   // M is always a multiple of 64 here
        #pragma unroll
        for (int j = 0; j < 4; j++) {
            const int n = n0 + tx * 4 + j;
            if (n >= N) continue;
            float v = acc[i][j] + bias[n];
            if (MODE == MODE_ENC) {
                v = tanhf(v + timev[m] * wt[n]);
            } else if (MODE == MODE_TANH) {
                v = tanhf(v);
            } else if (MODE == MODE_EULER) {
                v = C[(size_t)m * N + n] + DT * v;
            } else if (MODE == MODE_QKV) {
                v += eco[(size_t)(m >> 10) * Hc + n];          // b = m / S
                if (trandat[(size_t)m * Hc + (Hc - 1)] == 0.f) v = 0.f;
            }
            C[(size_t)m * N + n] = v;
        }
    }
}

// ---------------------------------------------------------------------------
// Attention: one block handles QT=8 query rows of one batch.
// scores -> softmax (in LDS) -> ctx. qkv layout: [3][B][S][H].
// ---------------------------------------------------------------------------
__global__ __launch_bounds__(256) void attn_kernel(
    const float* __restrict__ qkv, float* __restrict__ ctx)
{
    const int t = threadIdx.x;
    const int blk = blockIdx.x;
    const int b = blk / (Sc / QT);
    const int q0 = (blk % (Sc / QT)) * QT;
    const size_t plane = (size_t)Bc * Sc * Hc;
    const float* Qp = qkv + ((size_t)b * Sc + q0) * Hc;
    const float* Kp = qkv + plane + (size_t)b * Sc * Hc;
    const float* Vp = qkv + 2 * plane + (size_t)b * Sc * Hc;

    __shared__ float qs[QT][Hc];    // 8 KB
    __shared__ float sc[QT][Sc];    // 32 KB
    __shared__ float red4[4];

    #pragma unroll
    for (int r = 0; r < QT; r++) qs[r][t] = Qp[(size_t)r * Hc + t];
    __syncthreads();

    const float scale = 0.0625f;    // 1/sqrt(256)

    // ---- scores: each thread owns 4 keys (t, t+256, ...) ----
    for (int kb = 0; kb < Sc; kb += 256) {
        const int k = kb + t;
        const float4* K4 = (const float4*)(Kp + (size_t)k * Hc);
        float acc[QT] = {};
        for (int i = 0; i < Hc / 4; i++) {
            const float4 kv = K4[i];
            #pragma unroll
            for (int r = 0; r < QT; r++) {
                const float4 qv = *(const float4*)&qs[r][i * 4];
                acc[r] = fmaf(kv.x, qv.x,
                         fmaf(kv.y, qv.y,
                         fmaf(kv.z, qv.z,
                         fmaf(kv.w, qv.w, acc[r]))));
            }
        }
        #pragma unroll
        for (int r = 0; r < QT; r++) sc[r][k] = acc[r] * scale;
    }
    __syncthreads();

    // ---- softmax, row by row ----
    const int lane = t & 63, wv = t >> 6;
    for (int r = 0; r < QT; r++) {
        float mx = -1e30f;
        for (int k = t; k < Sc; k += 256) mx = fmaxf(mx, sc[r][k]);
        #pragma unroll
        for (int o = 32; o > 0; o >>= 1) mx = fmaxf(mx, __shfl_down(mx, o, 64));
        if (lane == 0) red4[wv] = mx;
        __syncthreads();
        mx = fmaxf(fmaxf(red4[0], red4[1]), fmaxf(red4[2], red4[3]));
        __syncthreads();

        float sum = 0.f;
        for (int k = t; k < Sc; k += 256) {
            const float e = __expf(sc[r][k] - mx);
            sc[r][k] = e;
            sum += e;
        }
        #pragma unroll
        for (int o = 32; o > 0; o >>= 1) sum += __shfl_down(sum, o, 64);
        if (lane == 0) red4[wv] = sum;
        __syncthreads();
        sum = red4[0] + red4[1] + red4[2] + red4[3];
        const float inv = 1.f / sum;
        for (int k = t; k < Sc; k += 256) sc[r][k] *= inv;
        __syncthreads();
    }

    // ---- ctx: thread t owns output channel t; float4 over the key axis ----
    float acc[QT] = {};
    for (int k = 0; k < Sc; k += 4) {
        const float v0 = Vp[(size_t)(k + 0) * Hc + t];
        const float v1 = Vp[(size_t)(k + 1) * Hc + t];
        const float v2 = Vp[(size_t)(k + 2) * Hc + t];
        const float v3 = Vp[(size_t)(k + 3) * Hc + t];
        #pragma unroll
        for (int r = 0; r < QT; r++) {
            const float4 s4 = *(const float4*)&sc[r][k];
            acc[r] = fmaf(s4.x, v0,
                     fmaf(s4.y, v1,
                     fmaf(s4.z, v2,
                     fmaf(s4.w, v3, acc[r]))));
        }
    }
    #pragma unroll
    for (int r = 0; r < QT; r++)
        ctx[((size_t)b * Sc + q0 + r) * Hc + t] = acc[r];
}

// ---------------------------------------------------------------------------
extern "C" void kernel_launch(void* const* d_in, const int* in_sizes, int n_in,
                              void* d_out, int out_size, void* d_ws, size_t ws_size,
                              hipStream_t stream)
{
    const float* eco_data = (const float*)d_in[0];
    const float* tran     = (const float*)d_in[1];
    // d_in[2] tran_data_label: unused. d_in[4] time_y: unused (concat+slice == time_x).
    const float* time_x   = (const float*)d_in[3];
    // d_in[5] alpha: unused.
    const float* W_eco    = (const float*)d_in[6];
    const float* b_eco    = (const float*)d_in[7];
    const float* W_in     = (const float*)d_in[8];
    const float* W_t      = (const float*)d_in[9];
    const float* b_in     = (const float*)d_in[10];
    const float* W_f1     = (const float*)d_in[11];
    const float* b_f1     = (const float*)d_in[12];
    const float* W_f2     = (const float*)d_in[13];
    const float* b_f2     = (const float*)d_in[14];
    const float* W_out    = (const float*)d_in[15];
    const float* b_out    = (const float*)d_in[16];
    const float* W_lin    = (const float*)d_in[17];
    const float* b_lin    = (const float*)d_in[18];
    float* out = (float*)d_out;

    // Workspace layout (floats): eco_vec | h[3][M][L] | hid[M][O] | qkv[3][M][H]
    float* eco_vec = (float*)d_ws;                       // 8192
    float* h    = eco_vec + 8192;                        // 19,660,800
    float* hid  = h + (size_t)3 * Mtot * Lc;             // 6,553,600
    float* qkvb = hid + (size_t)Mtot * Oc;               // 25,165,824
    float* ctx  = h;                                     // reuse: h dead after QKV

    eco_kernel<<<Bc, Hc, 0, stream>>>(eco_data, W_eco, b_eco, eco_vec);

    const dim3 blk(256);
    const dim3 gL(4, Mtot / 64);   // N=200/256 -> 4 col tiles
    // encode: h_k = tanh(tran @ W_in[k] + time_x*W_t[k] + b_in[k])
    for (int k = 0; k < 3; k++)
        gemm_ep<MODE_ENC><<<gL, blk, 0, stream>>>(
            tran, W_in + (size_t)k * Hc * Lc, b_in + k * Lc,
            h + (size_t)k * Mtot * Lc, Mtot, Lc, Hc,
            time_x, W_t + k * Lc, nullptr, nullptr);

    // Euler: h += DT * (tanh(h@W_f1+b1) @ W_f2 + b2)
    for (int it = 0; it < 4; it++) {
        for (int k = 0; k < 3; k++) {
            gemm_ep<MODE_TANH><<<gL, blk, 0, stream>>>(
                h + (size_t)k * Mtot * Lc, W_f1 + (size_t)k * Lc * Oc, b_f1 + k * Oc,
                hid, Mtot, Oc, Lc, nullptr, nullptr, nullptr, nullptr);
            gemm_ep<MODE_EULER><<<gL, blk, 0, stream>>>(
                hid, W_f2 + (size_t)k * Oc * Lc, b_f2 + k * Lc,
                h + (size_t)k * Mtot * Lc, Mtot, Lc, Oc, nullptr, nullptr, nullptr, nullptr);
        }
    }

    // qkv_k = (h_k @ W_out[k] + b_out[k] + eco_vec[b]) * mask
    for (int k = 0; k < 3; k++)
        gemm_ep<MODE_QKV><<<gL, blk, 0, stream>>>(
            h + (size_t)k * Mtot * Lc, W_out + (size_t)k * Lc * Hc, b_out + k * Hc,
            qkvb + (size_t)k * Mtot * Hc, Mtot, Hc, Lc,
            nullptr, nullptr, eco_vec, tran);

    attn_kernel<<<Bc * Sc / QT, 256, 0, stream>>>(qkvb, ctx);

    // out = ctx @ W_lin + b_lin
    const dim3 gO(2, Mtot / 64);
    gemm_ep<MODE_OUT><<<gO, blk, 0, stream>>>(
        ctx, W_lin, b_lin, out, Mtot, Pc, Hc, nullptr, nullptr, nullptr, nullptr);
}

// Round 2
// 1616.760 us; speedup vs baseline: 2.1792x; 2.1792x over previous
//
#include <hip/hip_runtime.h>

// Problem constants (fixed by the reference)
constexpr int Bc = 32, Sc = 1024, Hc = 256, Pc = 96, Lc = 200, Oc = 200, Ec = 64;
constexpr int Mtot = Bc * Sc;   // 32768 rows for all row-major GEMMs
constexpr float DT = 0.25f;     // 1/N_EULER
constexpr int QT = 8;           // q-rows per attention block

enum { MODE_ENC = 0, MODE_TANH = 1, MODE_EULER = 2, MODE_QKV = 3, MODE_OUT = 4 };

typedef short bf16x8 __attribute__((ext_vector_type(8)));
typedef float f32x4 __attribute__((ext_vector_type(4)));
typedef unsigned short u16x8 __attribute__((ext_vector_type(8)));

__device__ inline unsigned short f2bf(float x) {
    union { float f; unsigned int u; } v; v.f = x;
    unsigned int r = v.u + 0x7FFFu + ((v.u >> 16) & 1u);   // RNE
    return (unsigned short)(r >> 16);
}

// ---------------------------------------------------------------------------
// eco_vec[b,h] = eco_data[b,:] @ W_eco[:,h] + b_eco[h]
// ---------------------------------------------------------------------------
__global__ __launch_bounds__(256) void eco_kernel(
    const float* __restrict__ eco_data, const float* __restrict__ W_eco,
    const float* __restrict__ b_eco, float* __restrict__ eco_vec)
{
    const int b = blockIdx.x, h = threadIdx.x;
    float acc = b_eco[h];
    #pragma unroll
    for (int e = 0; e < Ec; e++)
        acc = fmaf(eco_data[b * Ec + e], W_eco[(size_t)e * Hc + h], acc);
    eco_vec[(size_t)b * Hc + h] = acc;
}

// ---------------------------------------------------------------------------
// Weight transpose + cast: W fp32 [K][N] (z slices) -> WT bf16 [Npad][Kpad],
// zero-padded so the GEMM needs no K/N bounds checks on B.
// ---------------------------------------------------------------------------
__global__ void wtrans_kernel(const float* __restrict__ W, unsigned short* __restrict__ WT,
                              int K, int N, int Kpad, int Npad)
{
    const int z = blockIdx.z;
    const int n = blockIdx.x * 16 + threadIdx.x;
    const int k = blockIdx.y * 16 + threadIdx.y;
    if (n >= Npad || k >= Kpad) return;
    float v = (n < N && k < K) ? W[(size_t)z * K * N + (size_t)k * N + n] : 0.f;
    WT[(size_t)z * Npad * Kpad + (size_t)n * Kpad + k] = f2bf(v);
}

// ---------------------------------------------------------------------------
// bf16 MFMA GEMM, 128x128 tile, 4 waves of 64x64, 16x16x32 MFMA.
// C = epilogue(A[M,K] @ W[K,N] + bias[N]); W passed pre-transposed bf16
// [Npad][Kpad]. A is fp32 or bf16 in global, cast during LDS staging.
// ---------------------------------------------------------------------------
template <int MODE, typename TA>
__global__ __launch_bounds__(256) void mfma_gemm(
    const TA* __restrict__ A, const unsigned short* __restrict__ WT,
    const float* __restrict__ bias, void* __restrict__ Cv,
    int M, int N, int K, int Kpad,
    size_t aStrideZ, size_t wStrideZ, size_t bStrideZ, size_t cStrideZ,
    const float* __restrict__ timev, const float* __restrict__ wtv,
    const float* __restrict__ eco, const float* __restrict__ trandat)
{
    constexpr int LDS_S = 40;   // LDS row stride (elements): 32 + 8 pad -> conflict-free frags
    __shared__ unsigned short As[128 * LDS_S];
    __shared__ unsigned short Bs[128 * LDS_S];

    const int tid = threadIdx.x;
    const int z = blockIdx.z;
    const int m0 = blockIdx.y * 128;
    const int n0 = blockIdx.x * 128;

    A   += (size_t)z * aStrideZ;
    WT  += (size_t)z * wStrideZ;
    bias += (size_t)z * bStrideZ;
    float* Cf = (float*)Cv + (size_t)z * cStrideZ;
    unsigned short* Cu = (unsigned short*)Cv + (size_t)z * cStrideZ;
    const float* wtp = wtv ? (wtv + (size_t)z * Lc) : nullptr;

    const int lane = tid & 63, wave = tid >> 6;
    const int wm = (wave & 1) * 64, wn = (wave >> 1) * 64;
    const int fm = lane & 15, fq = lane >> 4;

    f32x4 acc[4][4];
    #pragma unroll
    for (int i = 0; i < 4; i++)
        #pragma unroll
        for (int j = 0; j < 4; j++)
            acc[i][j] = (f32x4){0.f, 0.f, 0.f, 0.f};

    for (int k0 = 0; k0 < K; k0 += 32) {
        if (k0) __syncthreads();
        // ---- A tile: 128 rows x 32 k, cast to bf16 ----
        #pragma unroll
        for (int i = 0; i < 4; i++) {
            const int f = i * 256 + tid;     // 1024 4-elem chunks
            const int row = f >> 3, kq = f & 7;
            const int k = k0 + kq * 4;
            ushort4 s;
            if constexpr (sizeof(TA) == 4) {
                float4 v = {0.f, 0.f, 0.f, 0.f};
                if (k < K) v = *(const float4*)((const float*)A + (size_t)(m0 + row) * K + k);
                s.x = f2bf(v.x); s.y = f2bf(v.y); s.z = f2bf(v.z); s.w = f2bf(v.w);
            } else {
                s = make_ushort4(0, 0, 0, 0);
                if (k < K) s = *(const ushort4*)((const unsigned short*)A + (size_t)(m0 + row) * K + k);
            }
            *(ushort4*)&As[row * LDS_S + kq * 4] = s;
        }
        // ---- B tile: 128 n-rows x 32 k from WT (pre-padded, no bounds) ----
        #pragma unroll
        for (int i = 0; i < 2; i++) {
            const int f = i * 256 + tid;     // 512 8-elem chunks
            const int row = f >> 2, q = f & 3;
            u16x8 v = *(const u16x8*)(WT + (size_t)(n0 + row) * Kpad + k0 + q * 8);
            *(u16x8*)&Bs[row * LDS_S + q * 8] = v;
        }
        __syncthreads();

        bf16x8 af[4], bf[4];
        #pragma unroll
        for (int mi = 0; mi < 4; mi++)
            af[mi] = *(const bf16x8*)&As[(wm + mi * 16 + fm) * LDS_S + fq * 8];
        #pragma unroll
        for (int nj = 0; nj < 4; nj++)
            bf[nj] = *(const bf16x8*)&Bs[(wn + nj * 16 + fm) * LDS_S + fq * 8];
        #pragma unroll
        for (int mi = 0; mi < 4; mi++)
            #pragma unroll
            for (int nj = 0; nj < 4; nj++)
                acc[mi][nj] = __builtin_amdgcn_mfma_f32_16x16x32_bf16(
                    af[mi], bf[nj], acc[mi][nj], 0, 0, 0);
    }

    // ---- epilogue: C/D layout col = lane&15, row = quad*4 + reg ----
    #pragma unroll
    for (int mi = 0; mi < 4; mi++) {
        #pragma unroll
        for (int nj = 0; nj < 4; nj++) {
            const int nn = n0 + wn + nj * 16 + fm;
            if (nn >= N) continue;
            const float bv = bias[nn];
            #pragma unroll
            for (int r = 0; r < 4; r++) {
                const int mm = m0 + wm + mi * 16 + fq * 4 + r;
                float v = acc[mi][nj][r] + bv;
                if (MODE == MODE_ENC) {
                    v = tanhf(v + timev[mm] * wtp[nn]);
                    Cf[(size_t)mm * N + nn] = v;
                } else if (MODE == MODE_TANH) {
                    Cu[(size_t)mm * N + nn] = f2bf(tanhf(v));
                } else if (MODE == MODE_EULER) {
                    Cf[(size_t)mm * N + nn] = Cf[(size_t)mm * N + nn] + DT * v;
                } else if (MODE == MODE_QKV) {
                    v += eco[(size_t)(mm >> 10) * Hc + nn];
                    if (trandat[(size_t)mm * Hc + (Hc - 1)] == 0.f) v = 0.f;
                    Cf[(size_t)mm * N + nn] = v;
                } else {
                    Cf[(size_t)mm * N + nn] = v;
                }
            }
        }
    }
}

// ---------------------------------------------------------------------------
// Attention (fp32, unchanged from round 1): one block = QT query rows.
// ---------------------------------------------------------------------------
__global__ __launch_bounds__(256) void attn_kernel(
    const float* __restrict__ qkv, float* __restrict__ ctx)
{
    const int t = threadIdx.x;
    const int blk = blockIdx.x;
    const int b = blk / (Sc / QT);
    const int q0 = (blk % (Sc / QT)) * QT;
    const size_t plane = (size_t)Bc * Sc * Hc;
    const float* Qp = qkv + ((size_t)b * Sc + q0) * Hc;
    const float* Kp = qkv + plane + (size_t)b * Sc * Hc;
    const float* Vp = qkv + 2 * plane + (size_t)b * Sc * Hc;

    __shared__ float qs[QT][Hc];
    __shared__ float sc[QT][Sc];
    __shared__ float red4[4];

    #pragma unroll
    for (int r = 0; r < QT; r++) qs[r][t] = Qp[(size_t)r * Hc + t];
    __syncthreads();

    const float scale = 0.0625f;

    for (int kb = 0; kb < Sc; kb += 256) {
        const int k = kb + t;
        const float4* K4 = (const float4*)(Kp + (size_t)k * Hc);
        float acc[QT] = {};
        for (int i = 0; i < Hc / 4; i++) {
            const float4 kv = K4[i];
            #pragma unroll
            for (int r = 0; r < QT; r++) {
                const float4 qv = *(const float4*)&qs[r][i * 4];
                acc[r] = fmaf(kv.x, qv.x,
                         fmaf(kv.y, qv.y,
                         fmaf(kv.z, qv.z,
                         fmaf(kv.w, qv.w, acc[r]))));
            }
        }
        #pragma unroll
        for (int r = 0; r < QT; r++) sc[r][k] = acc[r] * scale;
    }
    __syncthreads();

    const int lane = t & 63, wv = t >> 6;
    for (int r = 0; r < QT; r++) {
        float mx = -1e30f;
        for (int k = t; k < Sc; k += 256) mx = fmaxf(mx, sc[r][k]);
        #pragma unroll
        for (int o = 32; o > 0; o >>= 1) mx = fmaxf(mx, __shfl_down(mx, o, 64));
        if (lane == 0) red4[wv] = mx;
        __syncthreads();
        mx = fmaxf(fmaxf(red4[0], red4[1]), fmaxf(red4[2], red4[3]));
        __syncthreads();

        float sum = 0.f;
        for (int k = t; k < Sc; k += 256) {
            const float e = __expf(sc[r][k] - mx);
            sc[r][k] = e;
            sum += e;
        }
        #pragma unroll
        for (int o = 32; o > 0; o >>= 1) sum += __shfl_down(sum, o, 64);
        if (lane == 0) red4[wv] = sum;
        __syncthreads();
        sum = red4[0] + red4[1] + red4[2] + red4[3];
        const float inv = 1.f / sum;
        for (int k = t; k < Sc; k += 256) sc[r][k] *= inv;
        __syncthreads();
    }

    float acc[QT] = {};
    for (int k = 0; k < Sc; k += 4) {
        const float v0 = Vp[(size_t)(k + 0) * Hc + t];
        const float v1 = Vp[(size_t)(k + 1) * Hc + t];
        const float v2 = Vp[(size_t)(k + 2) * Hc + t];
        const float v3 = Vp[(size_t)(k + 3) * Hc + t];
        #pragma unroll
        for (int r = 0; r < QT; r++) {
            const float4 s4 = *(const float4*)&sc[r][k];
            acc[r] = fmaf(s4.x, v0,
                     fmaf(s4.y, v1,
                     fmaf(s4.z, v2,
                     fmaf(s4.w, v3, acc[r]))));
        }
    }
    #pragma unroll
    for (int r = 0; r < QT; r++)
        ctx[((size_t)b * Sc + q0 + r) * Hc + t] = acc[r];
}

// ---------------------------------------------------------------------------
extern "C" void kernel_launch(void* const* d_in, const int* in_sizes, int n_in,
                              void* d_out, int out_size, void* d_ws, size_t ws_size,
                              hipStream_t stream)
{
    const float* eco_data = (const float*)d_in[0];
    const float* tran     = (const float*)d_in[1];
    const float* time_x   = (const float*)d_in[3];
    const float* W_eco    = (const float*)d_in[6];
    const float* b_eco    = (const float*)d_in[7];
    const float* W_in     = (const float*)d_in[8];
    const float* W_t      = (const float*)d_in[9];
    const float* b_in     = (const float*)d_in[10];
    const float* W_f1     = (const float*)d_in[11];
    const float* b_f1     = (const float*)d_in[12];
    const float* W_f2     = (const float*)d_in[13];
    const float* b_f2     = (const float*)d_in[14];
    const float* W_out    = (const float*)d_in[15];
    const float* b_out    = (const float*)d_in[16];
    const float* W_lin    = (const float*)d_in[17];
    const float* b_lin    = (const float*)d_in[18];
    float* out = (float*)d_out;

    // Workspace (floats): eco_vec | h[3][M][L] fp32 | qkv[3][M][H] fp32 | WT bf16
    // hid bf16 [3][M][O] aliases qkv (dead before qkv written); ctx aliases h.
    float* eco_vec = (float*)d_ws;                        // 8192 f
    float* h   = eco_vec + 8192;                          // 19,660,800 f
    float* qkv = h + (size_t)3 * Mtot * Lc;               // 25,165,824 f
    unsigned short* hid = (unsigned short*)qkv;           // alias
    float* ctx = h;                                       // alias
    unsigned short* WinT  = (unsigned short*)(qkv + (size_t)3 * Mtot * Hc);
    unsigned short* Wf1T  = WinT  + (size_t)3 * 256 * 256;
    unsigned short* Wf2T  = Wf1T  + (size_t)3 * 256 * 224;
    unsigned short* WoutT = Wf2T  + (size_t)3 * 256 * 224;
    unsigned short* WlinT = WoutT + (size_t)3 * 256 * 224;  // 128*256

    eco_kernel<<<Bc, Hc, 0, stream>>>(eco_data, W_eco, b_eco, eco_vec);

    const dim3 tb(16, 16);
    wtrans_kernel<<<dim3(16, 16, 3), tb, 0, stream>>>(W_in,  WinT,  256, 200, 256, 256);
    wtrans_kernel<<<dim3(16, 14, 3), tb, 0, stream>>>(W_f1,  Wf1T,  200, 200, 224, 256);
    wtrans_kernel<<<dim3(16, 14, 3), tb, 0, stream>>>(W_f2,  Wf2T,  200, 200, 224, 256);
    wtrans_kernel<<<dim3(16, 14, 3), tb, 0, stream>>>(W_out, WoutT, 200, 256, 224, 256);
    wtrans_kernel<<<dim3(8,  16, 1), tb, 0, stream>>>(W_lin, WlinT, 256,  96, 256, 128);

    const dim3 blk(256);
    const size_t ML = (size_t)Mtot * Lc, MH = (size_t)Mtot * Hc;

    // encode: h_k = tanh(tran @ W_in[k] + time_x*W_t[k] + b_in[k])
    mfma_gemm<MODE_ENC, float><<<dim3(2, 256, 3), blk, 0, stream>>>(
        tran, WinT, b_in, h, Mtot, Lc, Hc, 256,
        0, 65536, Lc, ML, time_x, W_t, nullptr, nullptr);

    // Euler: h += DT * (tanh(h@W_f1+b1) @ W_f2 + b2)
    for (int it = 0; it < 4; it++) {
        mfma_gemm<MODE_TANH, float><<<dim3(2, 256, 3), blk, 0, stream>>>(
            h, Wf1T, b_f1, hid, Mtot, Oc, Lc, 224,
            ML, 57344, Oc, ML, nullptr, nullptr, nullptr, nullptr);
        mfma_gemm<MODE_EULER, unsigned short><<<dim3(2, 256, 3), blk, 0, stream>>>(
            hid, Wf2T, b_f2, h, Mtot, Lc, Oc, 224,
            ML, 57344, Lc, ML, nullptr, nullptr, nullptr, nullptr);
    }

    // qkv_k = (h_k @ W_out[k] + b_out[k] + eco_vec[b]) * mask
    mfma_gemm<MODE_QKV, float><<<dim3(2, 256, 3), blk, 0, stream>>>(
        h, WoutT, b_out, qkv, Mtot, Hc, Lc, 224,
        ML, 57344, Hc, MH, nullptr, nullptr, eco_vec, tran);

    attn_kernel<<<Bc * Sc / QT, 256, 0, stream>>>(qkv, ctx);

    // out = ctx @ W_lin + b_lin
    mfma_gemm<MODE_OUT, float><<<dim3(1, 256, 1), blk, 0, stream>>>(
        ctx, WlinT, b_lin, out, Mtot, Pc, Hc, 256,
        0, 0, 0, 0, nullptr, nullptr, nullptr, nullptr);
}

// Round 3
// 907.992 us; speedup vs baseline: 3.8802x; 1.7806x over previous
//
#include <hip/hip_runtime.h>

// Problem constants (fixed by the reference)
constexpr int Bc = 32, Sc = 1024, Hc = 256, Pc = 96, Lc = 200, Oc = 200, Ec = 64;
constexpr int Mtot = Bc * Sc;   // 32768 rows for all row-major GEMMs
constexpr float DT = 0.25f;     // 1/N_EULER

enum { MODE_ENC = 0, MODE_TANH = 1, MODE_EULER = 2, MODE_QKV = 3, MODE_OUT = 4,
       MODE_BF16OUT = 5 };

typedef short bf16x8 __attribute__((ext_vector_type(8)));
typedef float f32x4 __attribute__((ext_vector_type(4)));
typedef unsigned short u16x8 __attribute__((ext_vector_type(8)));

__device__ inline unsigned short f2bf(float x) {
    union { float f; unsigned int u; } v; v.f = x;
    unsigned int r = v.u + 0x7FFFu + ((v.u >> 16) & 1u);   // RNE
    return (unsigned short)(r >> 16);
}
__device__ inline float bf2f(unsigned short x) {
    union { unsigned int u; float f; } v; v.u = ((unsigned int)x) << 16;
    return v.f;
}

// ---------------------------------------------------------------------------
__global__ __launch_bounds__(256) void eco_kernel(
    const float* __restrict__ eco_data, const float* __restrict__ W_eco,
    const float* __restrict__ b_eco, float* __restrict__ eco_vec)
{
    const int b = blockIdx.x, h = threadIdx.x;
    float acc = b_eco[h];
    #pragma unroll
    for (int e = 0; e < Ec; e++)
        acc = fmaf(eco_data[b * Ec + e], W_eco[(size_t)e * Hc + h], acc);
    eco_vec[(size_t)b * Hc + h] = acc;
}

// ---------------------------------------------------------------------------
// W fp32 [K][N] (z slices) -> WT bf16 [Npad][Kpad], zero-padded.
// ---------------------------------------------------------------------------
__global__ void wtrans_kernel(const float* __restrict__ W, unsigned short* __restrict__ WT,
                              int K, int N, int Kpad, int Npad)
{
    const int z = blockIdx.z;
    const int n = blockIdx.x * 16 + threadIdx.x;
    const int k = blockIdx.y * 16 + threadIdx.y;
    if (n >= Npad || k >= Kpad) return;
    float v = (n < N && k < K) ? W[(size_t)z * K * N + (size_t)k * N + n] : 0.f;
    WT[(size_t)z * Npad * Kpad + (size_t)n * Kpad + k] = f2bf(v);
}

// ---------------------------------------------------------------------------
// bf16 MFMA GEMM, 128x128 tile, 4 waves of 64x64, 16x16x32 MFMA.
// C = epilogue(A[M,K] @ B^T + bias); B passed as bf16 [Npad][Kpad] (n-major,
// contiguous k). A fp32 or bf16, cast during LDS staging.
// ---------------------------------------------------------------------------
template <int MODE, typename TA>
__global__ __launch_bounds__(256) void mfma_gemm(
    const TA* __restrict__ A, const unsigned short* __restrict__ WT,
    const float* __restrict__ bias, void* __restrict__ Cv,
    int M, int N, int K, int Kpad,
    size_t aStrideZ, size_t wStrideZ, size_t bStrideZ, size_t cStrideZ,
    const float* __restrict__ timev, const float* __restrict__ wtv,
    const float* __restrict__ eco, const float* __restrict__ trandat,
    unsigned short* __restrict__ Ck, unsigned short* __restrict__ Cvt)
{
    constexpr int LDS_S = 40;   // 32 + 8 pad -> conflict-free fragment reads
    __shared__ unsigned short As[128 * LDS_S];
    __shared__ unsigned short Bs[128 * LDS_S];

    const int tid = threadIdx.x;
    const int z = blockIdx.z;
    const int m0 = blockIdx.y * 128;
    const int n0 = blockIdx.x * 128;

    A    += (size_t)z * aStrideZ;
    WT   += (size_t)z * wStrideZ;
    bias += (size_t)z * bStrideZ;
    float* Cf = (float*)Cv + (size_t)z * cStrideZ;
    unsigned short* Cu = (unsigned short*)Cv + (size_t)z * cStrideZ;
    const float* wtp = wtv ? (wtv + (size_t)z * Lc) : nullptr;

    const int lane = tid & 63, wave = tid >> 6;
    const int wm = (wave & 1) * 64, wn = (wave >> 1) * 64;
    const int fm = lane & 15, fq = lane >> 4;

    f32x4 acc[4][4];
    #pragma unroll
    for (int i = 0; i < 4; i++)
        #pragma unroll
        for (int j = 0; j < 4; j++)
            acc[i][j] = (f32x4){0.f, 0.f, 0.f, 0.f};

    for (int k0 = 0; k0 < K; k0 += 32) {
        if (k0) __syncthreads();
        // ---- A tile: 128 rows x 32 k ----
        #pragma unroll
        for (int i = 0; i < 4; i++) {
            const int f = i * 256 + tid;
            const int row = f >> 3, kq = f & 7;
            const int k = k0 + kq * 4;
            ushort4 s;
            if constexpr (sizeof(TA) == 4) {
                float4 v = {0.f, 0.f, 0.f, 0.f};
                if (k < K) v = *(const float4*)((const float*)A + (size_t)(m0 + row) * K + k);
                s.x = f2bf(v.x); s.y = f2bf(v.y); s.z = f2bf(v.z); s.w = f2bf(v.w);
            } else {
                s = make_ushort4(0, 0, 0, 0);
                if (k < K) s = *(const ushort4*)((const unsigned short*)A + (size_t)(m0 + row) * K + k);
            }
            *(ushort4*)&As[row * LDS_S + kq * 4] = s;
        }
        // ---- B tile: 128 n-rows x 32 k (pre-padded, no bounds) ----
        #pragma unroll
        for (int i = 0; i < 2; i++) {
            const int f = i * 256 + tid;
            const int row = f >> 2, q = f & 3;
            u16x8 v = *(const u16x8*)(WT + (size_t)(n0 + row) * Kpad + k0 + q * 8);
            *(u16x8*)&Bs[row * LDS_S + q * 8] = v;
        }
        __syncthreads();

        bf16x8 af[4], bfr[4];
        #pragma unroll
        for (int mi = 0; mi < 4; mi++)
            af[mi] = *(const bf16x8*)&As[(wm + mi * 16 + fm) * LDS_S + fq * 8];
        #pragma unroll
        for (int nj = 0; nj < 4; nj++)
            bfr[nj] = *(const bf16x8*)&Bs[(wn + nj * 16 + fm) * LDS_S + fq * 8];
        #pragma unroll
        for (int mi = 0; mi < 4; mi++)
            #pragma unroll
            for (int nj = 0; nj < 4; nj++)
                acc[mi][nj] = __builtin_amdgcn_mfma_f32_16x16x32_bf16(
                    af[mi], bfr[nj], acc[mi][nj], 0, 0, 0);
    }

    // ---- epilogue: C/D layout col = lane&15, row = quad*4 + reg ----
    #pragma unroll
    for (int mi = 0; mi < 4; mi++) {
        #pragma unroll
        for (int nj = 0; nj < 4; nj++) {
            const int nn = n0 + wn + nj * 16 + fm;
            if (nn >= N) continue;
            const float bv = (MODE == MODE_BF16OUT) ? 0.f : bias[nn];
            #pragma unroll
            for (int r = 0; r < 4; r++) {
                const int mm = m0 + wm + mi * 16 + fq * 4 + r;
                float v = acc[mi][nj][r] + bv;
                if (MODE == MODE_ENC) {
                    v = tanhf(v + timev[mm] * wtp[nn]);
                    Cf[(size_t)mm * N + nn] = v;
                } else if (MODE == MODE_TANH) {
                    Cu[(size_t)mm * N + nn] = f2bf(tanhf(v));
                } else if (MODE == MODE_EULER) {
                    Cf[(size_t)mm * N + nn] = Cf[(size_t)mm * N + nn] + DT * v;
                } else if (MODE == MODE_QKV) {
                    v += eco[(size_t)(mm >> 10) * Hc + nn];
                    if (trandat[(size_t)mm * Hc + (Hc - 1)] == 0.f) v = 0.f;
                    const int bq = mm >> 10, sq = mm & (Sc - 1);
                    if (z == 0)      ((unsigned short*)Cv)[(size_t)mm * Hc + nn] = f2bf(v * 0.0625f);
                    else if (z == 1) Ck[(size_t)mm * Hc + nn] = f2bf(v);
                    else             Cvt[((size_t)bq * Hc + nn) * Sc + sq] = f2bf(v);
                } else if (MODE == MODE_BF16OUT) {
                    Cu[(size_t)mm * N + nn] = f2bf(v);
                } else {
                    Cf[(size_t)mm * N + nn] = v;
                }
            }
        }
    }
}

// ---------------------------------------------------------------------------
// Row softmax over P [32768][1024] bf16, in place. One wave per row.
// ---------------------------------------------------------------------------
__global__ __launch_bounds__(256) void softmax_kernel(unsigned short* __restrict__ P)
{
    const int row = blockIdx.x * 4 + (threadIdx.x >> 6);
    const int lane = threadIdx.x & 63;
    unsigned short* p = P + (size_t)row * Sc + lane * 16;
    const u16x8 a = *(const u16x8*)p;
    const u16x8 b = *(const u16x8*)(p + 8);
    float v[16];
    #pragma unroll
    for (int i = 0; i < 8; i++) { v[i] = bf2f(a[i]); v[8 + i] = bf2f(b[i]); }

    float mx = v[0];
    #pragma unroll
    for (int i = 1; i < 16; i++) mx = fmaxf(mx, v[i]);
    #pragma unroll
    for (int o = 32; o > 0; o >>= 1) mx = fmaxf(mx, __shfl_xor(mx, o, 64));

    float s = 0.f;
    #pragma unroll
    for (int i = 0; i < 16; i++) { v[i] = __expf(v[i] - mx); s += v[i]; }
    #pragma unroll
    for (int o = 32; o > 0; o >>= 1) s += __shfl_xor(s, o, 64);
    const float inv = 1.f / s;

    u16x8 oa, ob;
    #pragma unroll
    for (int i = 0; i < 8; i++) { oa[i] = f2bf(v[i] * inv); ob[i] = f2bf(v[8 + i] * inv); }
    *(u16x8*)p = oa;
    *(u16x8*)(p + 8) = ob;
}

// ---------------------------------------------------------------------------
extern "C" void kernel_launch(void* const* d_in, const int* in_sizes, int n_in,
                              void* d_out, int out_size, void* d_ws, size_t ws_size,
                              hipStream_t stream)
{
    const float* eco_data = (const float*)d_in[0];
    const float* tran     = (const float*)d_in[1];
    const float* time_x   = (const float*)d_in[3];
    const float* W_eco    = (const float*)d_in[6];
    const float* b_eco    = (const float*)d_in[7];
    const float* W_in     = (const float*)d_in[8];
    const float* W_t      = (const float*)d_in[9];
    const float* b_in     = (const float*)d_in[10];
    const float* W_f1     = (const float*)d_in[11];
    const float* b_f1     = (const float*)d_in[12];
    const float* W_f2     = (const float*)d_in[13];
    const float* b_f2     = (const float*)d_in[14];
    const float* W_out    = (const float*)d_in[15];
    const float* b_out    = (const float*)d_in[16];
    const float* W_lin    = (const float*)d_in[17];
    const float* b_lin    = (const float*)d_in[18];
    float* out = (float*)d_out;

    // Workspace: eco_vec f | h f[3][M][L] | Qb,Kb,VT bf16 | P bf16 | WT bf16
    // hid bf16 aliases P (dead before P). ctx bf16 aliases h (dead after QKV).
    float* eco_vec = (float*)d_ws;                               // 8192 f
    float* h   = eco_vec + 8192;                                 // 19,660,800 f
    unsigned short* Qb = (unsigned short*)(h + (size_t)3 * Mtot * Lc);
    unsigned short* Kb = Qb + (size_t)Mtot * Hc;                 // 8,388,608 each
    unsigned short* VT = Kb + (size_t)Mtot * Hc;
    unsigned short* P  = VT + (size_t)Mtot * Hc;                 // 33,554,432
    unsigned short* WinT  = P + (size_t)Mtot * Sc;
    unsigned short* Wf1T  = WinT  + (size_t)3 * 256 * 256;
    unsigned short* Wf2T  = Wf1T  + (size_t)3 * 256 * 224;
    unsigned short* WoutT = Wf2T  + (size_t)3 * 256 * 224;
    unsigned short* WlinT = WoutT + (size_t)3 * 256 * 224;
    unsigned short* hid = P;                                     // alias
    unsigned short* ctxb = (unsigned short*)h;                   // alias

    eco_kernel<<<Bc, Hc, 0, stream>>>(eco_data, W_eco, b_eco, eco_vec);

    const dim3 tb(16, 16);
    wtrans_kernel<<<dim3(16, 16, 3), tb, 0, stream>>>(W_in,  WinT,  256, 200, 256, 256);
    wtrans_kernel<<<dim3(16, 14, 3), tb, 0, stream>>>(W_f1,  Wf1T,  200, 200, 224, 256);
    wtrans_kernel<<<dim3(16, 14, 3), tb, 0, stream>>>(W_f2,  Wf2T,  200, 200, 224, 256);
    wtrans_kernel<<<dim3(16, 14, 3), tb, 0, stream>>>(W_out, WoutT, 200, 256, 224, 256);
    wtrans_kernel<<<dim3(8,  16, 1), tb, 0, stream>>>(W_lin, WlinT, 256,  96, 256, 128);

    const dim3 blk(256);
    const size_t ML = (size_t)Mtot * Lc, MH = (size_t)Mtot * Hc;

    // encode: h_k = tanh(tran @ W_in[k] + time_x*W_t[k] + b_in[k])
    mfma_gemm<MODE_ENC, float><<<dim3(2, 256, 3), blk, 0, stream>>>(
        tran, WinT, b_in, h, Mtot, Lc, Hc, 256,
        0, 65536, Lc, ML, time_x, W_t, nullptr, nullptr, nullptr, nullptr);

    // Euler: h += DT * (tanh(h@W_f1+b1) @ W_f2 + b2)
    for (int it = 0; it < 4; it++) {
        mfma_gemm<MODE_TANH, float><<<dim3(2, 256, 3), blk, 0, stream>>>(
            h, Wf1T, b_f1, hid, Mtot, Oc, Lc, 224,
            ML, 57344, Oc, ML, nullptr, nullptr, nullptr, nullptr, nullptr, nullptr);
        mfma_gemm<MODE_EULER, unsigned short><<<dim3(2, 256, 3), blk, 0, stream>>>(
            hid, Wf2T, b_f2, h, Mtot, Lc, Oc, 224,
            ML, 57344, Lc, ML, nullptr, nullptr, nullptr, nullptr, nullptr, nullptr);
    }

    // qkv: Q*scale, K, V^T written bf16 directly
    mfma_gemm<MODE_QKV, float><<<dim3(2, 256, 3), blk, 0, stream>>>(
        h, WoutT, b_out, Qb, Mtot, Hc, Lc, 224,
        ML, 57344, Hc, 0, nullptr, nullptr, eco_vec, tran, Kb, VT);

    // scores: P[b] = (Q*scale)[b] @ K[b]^T   (z = batch)
    mfma_gemm<MODE_BF16OUT, unsigned short><<<dim3(8, 8, 32), blk, 0, stream>>>(
        Qb, Kb, nullptr, P, Sc, Sc, Hc, Hc,
        (size_t)Sc * Hc, (size_t)Sc * Hc, 0, (size_t)Sc * Sc,
        nullptr, nullptr, nullptr, nullptr, nullptr, nullptr);

    softmax_kernel<<<Mtot / 4, blk, 0, stream>>>(P);

    // ctx: ctx[b] = P[b] @ V[b]  (B operand = V^T, contiguous k)
    mfma_gemm<MODE_BF16OUT, unsigned short><<<dim3(2, 8, 32), blk, 0, stream>>>(
        P, VT, nullptr, ctxb, Sc, Hc, Sc, Sc,
        (size_t)Sc * Sc, (size_t)Hc * Sc, 0, (size_t)Sc * Hc,
        nullptr, nullptr, nullptr, nullptr, nullptr, nullptr);

    // out = ctx @ W_lin + b_lin
    mfma_gemm<MODE_OUT, unsigned short><<<dim3(1, 256, 1), blk, 0, stream>>>(
        ctxb, WlinT, b_lin, out, Mtot, Pc, Hc, 256,
        0, 0, 0, 0, nullptr, nullptr, nullptr, nullptr, nullptr, nullptr);
}

// Round 4
// 668.755 us; speedup vs baseline: 5.2682x; 1.3577x over previous
//
#include <hip/hip_runtime.h>

// Problem constants (fixed by the reference)
constexpr int Bc = 32, Sc = 1024, Hc = 256, Pc = 96, Lc = 200, Oc = 200, Ec = 64;
constexpr int Mtot = Bc * Sc;
constexpr float DT = 0.25f;     // 1/N_EULER
constexpr int KP = 224;         // padded L/O dim (7*32)

enum { MODE_ENC = 0, MODE_QKV = 3, MODE_OUT = 4, MODE_BF16OUT = 5 };

typedef short bf16x8 __attribute__((ext_vector_type(8)));
typedef float f32x4 __attribute__((ext_vector_type(4)));
typedef unsigned short u16x8 __attribute__((ext_vector_type(8)));

__device__ inline unsigned short f2bf(float x) {
    union { float f; unsigned int u; } v; v.f = x;
    unsigned int r = v.u + 0x7FFFu + ((v.u >> 16) & 1u);   // RNE
    return (unsigned short)(r >> 16);
}
__device__ inline float bf2f(unsigned short x) {
    union { unsigned int u; float f; } v; v.u = ((unsigned int)x) << 16;
    return v.f;
}
__device__ inline float fast_tanh(float x) {
    float cx = fminf(fmaxf(x, -15.f), 15.f);
    float e = __expf(2.f * cx);
    return __fdividef(e - 1.f, e + 1.f);
}

// ---------------------------------------------------------------------------
__global__ __launch_bounds__(256) void eco_kernel(
    const float* __restrict__ eco_data, const float* __restrict__ W_eco,
    const float* __restrict__ b_eco, float* __restrict__ eco_vec)
{
    const int b = blockIdx.x, h = threadIdx.x;
    float acc = b_eco[h];
    #pragma unroll
    for (int e = 0; e < Ec; e++)
        acc = fmaf(eco_data[b * Ec + e], W_eco[(size_t)e * Hc + h], acc);
    eco_vec[(size_t)b * Hc + h] = acc;
}

// ---------------------------------------------------------------------------
// W fp32 [K][N] (z slices) -> WT bf16 [Npad][Kpad], zero-padded.
// ---------------------------------------------------------------------------
__global__ void wtrans_kernel(const float* __restrict__ W, unsigned short* __restrict__ WT,
                              int K, int N, int Kpad, int Npad)
{
    const int z = blockIdx.z;
    const int n = blockIdx.x * 16 + threadIdx.x;
    const int k = blockIdx.y * 16 + threadIdx.y;
    if (n >= Npad || k >= Kpad) return;
    float v = (n < N && k < K) ? W[(size_t)z * K * N + (size_t)k * N + n] : 0.f;
    WT[(size_t)z * Npad * Kpad + (size_t)n * Kpad + k] = f2bf(v);
}

// ---------------------------------------------------------------------------
// bf16 MFMA GEMM, 128x128 tile, 4 waves of 64x64, 16x16x32 MFMA.
// ---------------------------------------------------------------------------
template <int MODE, typename TA>
__global__ __launch_bounds__(256) void mfma_gemm(
    const TA* __restrict__ A, const unsigned short* __restrict__ WT,
    const float* __restrict__ bias, void* __restrict__ Cv,
    int M, int N, int K, int Kpad,
    size_t aStrideZ, size_t wStrideZ, size_t bStrideZ, size_t cStrideZ,
    const float* __restrict__ timev, const float* __restrict__ wtv,
    const float* __restrict__ eco, const float* __restrict__ trandat,
    unsigned short* __restrict__ Ck, unsigned short* __restrict__ Cvt)
{
    constexpr int LDS_S = 40;
    __shared__ unsigned short As[128 * LDS_S];
    __shared__ unsigned short Bs[128 * LDS_S];

    const int tid = threadIdx.x;
    const int z = blockIdx.z;
    const int m0 = blockIdx.y * 128;
    const int n0 = blockIdx.x * 128;

    A    += (size_t)z * aStrideZ;
    WT   += (size_t)z * wStrideZ;
    bias += (size_t)z * bStrideZ;
    float* Cf = (float*)Cv + (size_t)z * cStrideZ;
    unsigned short* Cu = (unsigned short*)Cv + (size_t)z * cStrideZ;
    const float* wtp = wtv ? (wtv + (size_t)z * Lc) : nullptr;

    const int lane = tid & 63, wave = tid >> 6;
    const int wm = (wave & 1) * 64, wn = (wave >> 1) * 64;
    const int fm = lane & 15, fq = lane >> 4;

    f32x4 acc[4][4];
    #pragma unroll
    for (int i = 0; i < 4; i++)
        #pragma unroll
        for (int j = 0; j < 4; j++)
            acc[i][j] = (f32x4){0.f, 0.f, 0.f, 0.f};

    for (int k0 = 0; k0 < K; k0 += 32) {
        if (k0) __syncthreads();
        #pragma unroll
        for (int i = 0; i < 4; i++) {
            const int f = i * 256 + tid;
            const int row = f >> 3, kq = f & 7;
            const int k = k0 + kq * 4;
            ushort4 s;
            if constexpr (sizeof(TA) == 4) {
                float4 v = {0.f, 0.f, 0.f, 0.f};
                if (k < K) v = *(const float4*)((const float*)A + (size_t)(m0 + row) * K + k);
                s.x = f2bf(v.x); s.y = f2bf(v.y); s.z = f2bf(v.z); s.w = f2bf(v.w);
            } else {
                s = make_ushort4(0, 0, 0, 0);
                if (k < K) s = *(const ushort4*)((const unsigned short*)A + (size_t)(m0 + row) * K + k);
            }
            *(ushort4*)&As[row * LDS_S + kq * 4] = s;
        }
        #pragma unroll
        for (int i = 0; i < 2; i++) {
            const int f = i * 256 + tid;
            const int row = f >> 2, q = f & 3;
            u16x8 v = *(const u16x8*)(WT + (size_t)(n0 + row) * Kpad + k0 + q * 8);
            *(u16x8*)&Bs[row * LDS_S + q * 8] = v;
        }
        __syncthreads();

        bf16x8 af[4], bfr[4];
        #pragma unroll
        for (int mi = 0; mi < 4; mi++)
            af[mi] = *(const bf16x8*)&As[(wm + mi * 16 + fm) * LDS_S + fq * 8];
        #pragma unroll
        for (int nj = 0; nj < 4; nj++)
            bfr[nj] = *(const bf16x8*)&Bs[(wn + nj * 16 + fm) * LDS_S + fq * 8];
        #pragma unroll
        for (int mi = 0; mi < 4; mi++)
            #pragma unroll
            for (int nj = 0; nj < 4; nj++)
                acc[mi][nj] = __builtin_amdgcn_mfma_f32_16x16x32_bf16(
                    af[mi], bfr[nj], acc[mi][nj], 0, 0, 0);
    }

    // epilogue: C/D layout col = lane&15, row = quad*4 + reg
    #pragma unroll
    for (int mi = 0; mi < 4; mi++) {
        #pragma unroll
        for (int nj = 0; nj < 4; nj++) {
            const int nn = n0 + wn + nj * 16 + fm;
            if (nn >= N) continue;
            const float bv = (MODE == MODE_BF16OUT) ? 0.f
                           : ((MODE == MODE_ENC && nn >= Lc) ? 0.f : bias[nn]);
            #pragma unroll
            for (int r = 0; r < 4; r++) {
                const int mm = m0 + wm + mi * 16 + fq * 4 + r;
                float v = acc[mi][nj][r] + bv;
                if (MODE == MODE_ENC) {
                    float vv = (nn < Lc) ? fast_tanh(v + timev[mm] * wtp[nn]) : 0.f;
                    Cu[(size_t)mm * N + nn] = f2bf(vv);
                } else if (MODE == MODE_QKV) {
                    v += eco[(size_t)(mm >> 10) * Hc + nn];
                    if (trandat[(size_t)mm * Hc + (Hc - 1)] == 0.f) v = 0.f;
                    const int bq = mm >> 10, sq = mm & (Sc - 1);
                    if (z == 0)      ((unsigned short*)Cv)[(size_t)mm * Hc + nn] = f2bf(v * 0.0625f);
                    else if (z == 1) Ck[(size_t)mm * Hc + nn] = f2bf(v);
                    else             Cvt[((size_t)bq * Hc + nn) * Sc + sq] = f2bf(v);
                } else if (MODE == MODE_BF16OUT) {
                    Cu[(size_t)mm * N + nn] = f2bf(v);
                } else {
                    Cf[(size_t)mm * N + nn] = v;
                }
            }
        }
    }
}

// ---------------------------------------------------------------------------
// Fused 4-iteration Euler solve. Block = 64 rows of one k-slice; h kept in
// LDS (bf16); hid lives in registers + small LDS chunk for layout transform.
// Waves tile 2x2: each wave 32 rows x 112 cols.
// ---------------------------------------------------------------------------
__global__ __launch_bounds__(256) void euler_fused(
    unsigned short* __restrict__ hg,       // [3][M][224] bf16, in/out
    const unsigned short* __restrict__ W1, // [3][256][224] bf16
    const unsigned short* __restrict__ W2, // [3][256][224] bf16
    const float* __restrict__ b1g, const float* __restrict__ b2g)
{
    constexpr int HS = 232;   // h LDS stride
    constexpr int WS = 40;    // W chunk stride
    constexpr int CS = 40;    // hid chunk stride
    __shared__ unsigned short hs[64 * HS];    // 29,696 B
    __shared__ unsigned short ws[256 * WS];   // 20,480 B
    __shared__ unsigned short hc[64 * CS];    //  5,120 B

    const int tid = threadIdx.x;
    const int z = blockIdx.y;
    const int m0 = blockIdx.x * 64;
    unsigned short* hrow = hg + ((size_t)z * Mtot + m0) * KP;
    const unsigned short* W1z = W1 + (size_t)z * 256 * KP;
    const unsigned short* W2z = W2 + (size_t)z * 256 * KP;
    const float* b1 = b1g + z * Oc;
    const float* b2 = b2g + z * Lc;

    // stage h tile: 64 x 224
    #pragma unroll
    for (int i = 0; i < 7; i++) {
        const int f = i * 256 + tid;
        const int r = f / 28, c = (f % 28) * 8;
        *(u16x8*)&hs[r * HS + c] = *(const u16x8*)&hrow[(size_t)r * KP + c];
    }

    const int lane = tid & 63, w = tid >> 6;
    const int wm = (w & 1) * 32, wn = (w >> 1) * 112;
    const int fm = lane & 15, fq = lane >> 4;

    for (int it = 0; it < 4; it++) {
        // ---------- phase 1: hid = tanh(h @ W1 + b1) ----------
        f32x4 acc[2][7];
        #pragma unroll
        for (int mi = 0; mi < 2; mi++)
            #pragma unroll
            for (int nj = 0; nj < 7; nj++)
                acc[mi][nj] = (f32x4){0.f, 0.f, 0.f, 0.f};

        for (int k0 = 0; k0 < KP; k0 += 32) {
            __syncthreads();   // protects ws reuse (and initial h staging)
            #pragma unroll
            for (int i = 0; i < 4; i++) {
                const int f = i * 256 + tid;
                const int r = f >> 2, q = f & 3;
                *(u16x8*)&ws[r * WS + q * 8] =
                    *(const u16x8*)&W1z[(size_t)r * KP + k0 + q * 8];
            }
            __syncthreads();
            bf16x8 af[2], bf[7];
            #pragma unroll
            for (int mi = 0; mi < 2; mi++)
                af[mi] = *(const bf16x8*)&hs[(wm + mi * 16 + fm) * HS + k0 + fq * 8];
            #pragma unroll
            for (int nj = 0; nj < 7; nj++)
                bf[nj] = *(const bf16x8*)&ws[(wn + nj * 16 + fm) * WS + fq * 8];
            #pragma unroll
            for (int mi = 0; mi < 2; mi++)
                #pragma unroll
                for (int nj = 0; nj < 7; nj++)
                    acc[mi][nj] = __builtin_amdgcn_mfma_f32_16x16x32_bf16(
                        af[mi], bf[nj], acc[mi][nj], 0, 0, 0);
        }

        // bias + tanh, pack to bf16 (C layout: col = fm, row = fq*4+r)
        unsigned short hidp[2][7][4];
        #pragma unroll
        for (int mi = 0; mi < 2; mi++)
            #pragma unroll
            for (int nj = 0; nj < 7; nj++) {
                const int nn = wn + nj * 16 + fm;
                const float bv = (nn < Oc) ? b1[nn] : 0.f;
                #pragma unroll
                for (int r = 0; r < 4; r++)
                    hidp[mi][nj][r] = f2bf(fast_tanh(acc[mi][nj][r] + bv));
            }

        // ---------- phase 2: h += DT * (hid @ W2 + b2) ----------
        f32x4 fac[2][7];
        #pragma unroll
        for (int mi = 0; mi < 2; mi++)
            #pragma unroll
            for (int nj = 0; nj < 7; nj++)
                fac[mi][nj] = (f32x4){0.f, 0.f, 0.f, 0.f};

        #pragma unroll
        for (int kc = 0; kc < 7; kc++) {
            const int k2 = kc * 32;
            __syncthreads();   // protects ws + hc reuse
            // write hid chunk cols [k2, k2+32) into hc (owning waves only)
            #pragma unroll
            for (int t2 = 0; t2 < 2; t2++) {
                const int nc0 = k2 + t2 * 16;
                if (nc0 >= wn && nc0 < wn + 112) {
                    const int nj = (nc0 - wn) >> 4;
                    #pragma unroll
                    for (int mi = 0; mi < 2; mi++)
                        #pragma unroll
                        for (int r = 0; r < 4; r++)
                            hc[(wm + mi * 16 + fq * 4 + r) * CS + t2 * 16 + fm] =
                                hidp[mi][nj][r];
                }
            }
            // stage W2 chunk
            #pragma unroll
            for (int i = 0; i < 4; i++) {
                const int f = i * 256 + tid;
                const int r = f >> 2, q = f & 3;
                *(u16x8*)&ws[r * WS + q * 8] =
                    *(const u16x8*)&W2z[(size_t)r * KP + k2 + q * 8];
            }
            __syncthreads();
            bf16x8 af2[2], bf2[7];
            #pragma unroll
            for (int mi = 0; mi < 2; mi++)
                af2[mi] = *(const bf16x8*)&hc[(wm + mi * 16 + fm) * CS + fq * 8];
            #pragma unroll
            for (int nj = 0; nj < 7; nj++)
                bf2[nj] = *(const bf16x8*)&ws[(wn + nj * 16 + fm) * WS + fq * 8];
            #pragma unroll
            for (int mi = 0; mi < 2; mi++)
                #pragma unroll
                for (int nj = 0; nj < 7; nj++)
                    fac[mi][nj] = __builtin_amdgcn_mfma_f32_16x16x32_bf16(
                        af2[mi], bf2[nj], fac[mi][nj], 0, 0, 0);
        }

        // h update (each wave owns rows wm..wm+32, cols wn..wn+112)
        #pragma unroll
        for (int mi = 0; mi < 2; mi++)
            #pragma unroll
            for (int nj = 0; nj < 7; nj++) {
                const int nn = wn + nj * 16 + fm;
                const float bv = (nn < Lc) ? b2[nn] : 0.f;
                #pragma unroll
                for (int r = 0; r < 4; r++) {
                    const int row = wm + mi * 16 + fq * 4 + r;
                    const float fv = fac[mi][nj][r] + bv;
                    const float hv = bf2f(hs[row * HS + nn]) + DT * fv;
                    hs[row * HS + nn] = f2bf(hv);
                }
            }
    }
    __syncthreads();
    // write back h tile
    #pragma unroll
    for (int i = 0; i < 7; i++) {
        const int f = i * 256 + tid;
        const int r = f / 28, c = (f % 28) * 8;
        *(u16x8*)&hrow[(size_t)r * KP + c] = *(const u16x8*)&hs[r * HS + c];
    }
}

// ---------------------------------------------------------------------------
// Row softmax over P [32768][1024] bf16, in place. One wave per row.
// ---------------------------------------------------------------------------
__global__ __launch_bounds__(256) void softmax_kernel(unsigned short* __restrict__ P)
{
    const int row = blockIdx.x * 4 + (threadIdx.x >> 6);
    const int lane = threadIdx.x & 63;
    unsigned short* p = P + (size_t)row * Sc + lane * 16;
    const u16x8 a = *(const u16x8*)p;
    const u16x8 b = *(const u16x8*)(p + 8);
    float v[16];
    #pragma unroll
    for (int i = 0; i < 8; i++) { v[i] = bf2f(a[i]); v[8 + i] = bf2f(b[i]); }

    float mx = v[0];
    #pragma unroll
    for (int i = 1; i < 16; i++) mx = fmaxf(mx, v[i]);
    #pragma unroll
    for (int o = 32; o > 0; o >>= 1) mx = fmaxf(mx, __shfl_xor(mx, o, 64));

    float s = 0.f;
    #pragma unroll
    for (int i = 0; i < 16; i++) { v[i] = __expf(v[i] - mx); s += v[i]; }
    #pragma unroll
    for (int o = 32; o > 0; o >>= 1) s += __shfl_xor(s, o, 64);
    const float inv = 1.f / s;

    u16x8 oa, ob;
    #pragma unroll
    for (int i = 0; i < 8; i++) { oa[i] = f2bf(v[i] * inv); ob[i] = f2bf(v[8 + i] * inv); }
    *(u16x8*)p = oa;
    *(u16x8*)(p + 8) = ob;
}

// ---------------------------------------------------------------------------
extern "C" void kernel_launch(void* const* d_in, const int* in_sizes, int n_in,
                              void* d_out, int out_size, void* d_ws, size_t ws_size,
                              hipStream_t stream)
{
    const float* eco_data = (const float*)d_in[0];
    const float* tran     = (const float*)d_in[1];
    const float* time_x   = (const float*)d_in[3];
    const float* W_eco    = (const float*)d_in[6];
    const float* b_eco    = (const float*)d_in[7];
    const float* W_in     = (const float*)d_in[8];
    const float* W_t      = (const float*)d_in[9];
    const float* b_in     = (const float*)d_in[10];
    const float* W_f1     = (const float*)d_in[11];
    const float* b_f1     = (const float*)d_in[12];
    const float* W_f2     = (const float*)d_in[13];
    const float* b_f2     = (const float*)d_in[14];
    const float* W_out    = (const float*)d_in[15];
    const float* b_out    = (const float*)d_in[16];
    const float* W_lin    = (const float*)d_in[17];
    const float* b_lin    = (const float*)d_in[18];
    float* out = (float*)d_out;

    // Workspace: eco_vec f32 | hpad bf16[3][M][224] | Qb,Kb,VT bf16 | P bf16 | WT
    float* eco_vec = (float*)d_ws;                               // 8192 f
    unsigned short* hpad = (unsigned short*)(eco_vec + 8192);    // 22,020,096 u16
    unsigned short* Qb = hpad + (size_t)3 * Mtot * KP;
    unsigned short* Kb = Qb + (size_t)Mtot * Hc;
    unsigned short* VT = Kb + (size_t)Mtot * Hc;
    unsigned short* P  = VT + (size_t)Mtot * Hc;
    unsigned short* WinT  = P + (size_t)Mtot * Sc;
    unsigned short* Wf1T  = WinT  + (size_t)3 * 256 * 256;
    unsigned short* Wf2T  = Wf1T  + (size_t)3 * 256 * KP;
    unsigned short* WoutT = Wf2T  + (size_t)3 * 256 * KP;
    unsigned short* WlinT = WoutT + (size_t)3 * 256 * KP;
    unsigned short* ctxb = hpad;                                 // alias (h dead after qkv)

    eco_kernel<<<Bc, Hc, 0, stream>>>(eco_data, W_eco, b_eco, eco_vec);

    const dim3 tb(16, 16);
    wtrans_kernel<<<dim3(16, 16, 3), tb, 0, stream>>>(W_in,  WinT,  256, 200, 256, 256);
    wtrans_kernel<<<dim3(16, 14, 3), tb, 0, stream>>>(W_f1,  Wf1T,  200, 200, 224, 256);
    wtrans_kernel<<<dim3(16, 14, 3), tb, 0, stream>>>(W_f2,  Wf2T,  200, 200, 224, 256);
    wtrans_kernel<<<dim3(16, 14, 3), tb, 0, stream>>>(W_out, WoutT, 200, 256, 224, 256);
    wtrans_kernel<<<dim3(8,  16, 1), tb, 0, stream>>>(W_lin, WlinT, 256,  96, 256, 128);

    const dim3 blk(256);

    // encode: hpad_k = tanh(tran @ W_in[k] + time_x*W_t[k] + b_in[k]), bf16 out
    mfma_gemm<MODE_ENC, float><<<dim3(2, 256, 3), blk, 0, stream>>>(
        tran, WinT, b_in, hpad, Mtot, KP, Hc, 256,
        0, 65536, Lc, (size_t)Mtot * KP, time_x, W_t, nullptr, nullptr, nullptr, nullptr);

    // fused 4-step Euler solve (persistent per 64-row tile)
    euler_fused<<<dim3(Mtot / 64, 3), blk, 0, stream>>>(hpad, Wf1T, Wf2T, b_f1, b_f2);

    // qkv: Q*scale, K, V^T written bf16
    mfma_gemm<MODE_QKV, unsigned short><<<dim3(2, 256, 3), blk, 0, stream>>>(
        hpad, WoutT, b_out, Qb, Mtot, Hc, KP, KP,
        (size_t)Mtot * KP, 57344, Hc, 0, nullptr, nullptr, eco_vec, tran, Kb, VT);

    // scores: P[b] = (Q*scale)[b] @ K[b]^T
    mfma_gemm<MODE_BF16OUT, unsigned short><<<dim3(8, 8, 32), blk, 0, stream>>>(
        Qb, Kb, nullptr, P, Sc, Sc, Hc, Hc,
        (size_t)Sc * Hc, (size_t)Sc * Hc, 0, (size_t)Sc * Sc,
        nullptr, nullptr, nullptr, nullptr, nullptr, nullptr);

    softmax_kernel<<<Mtot / 4, blk, 0, stream>>>(P);

    // ctx: ctx[b] = P[b] @ V[b]  (B operand = V^T)
    mfma_gemm<MODE_BF16OUT, unsigned short><<<dim3(2, 8, 32), blk, 0, stream>>>(
        P, VT, nullptr, ctxb, Sc, Hc, Sc, Sc,
        (size_t)Sc * Sc, (size_t)Hc * Sc, 0, (size_t)Sc * Hc,
        nullptr, nullptr, nullptr, nullptr, nullptr, nullptr);

    // out = ctx @ W_lin + b_lin
    mfma_gemm<MODE_OUT, unsigned short><<<dim3(1, 256, 1), blk, 0, stream>>>(
        ctxb, WlinT, b_lin, out, Mtot, Pc, Hc, 256,
        0, 0, 0, 0, nullptr, nullptr, nullptr, nullptr, nullptr, nullptr);
}

// Round 5
// 588.943 us; speedup vs baseline: 5.9822x; 1.1355x over previous
//
#include <hip/hip_runtime.h>

// Problem constants (fixed by the reference)
constexpr int Bc = 32, Sc = 1024, Hc = 256, Pc = 96, Lc = 200, Oc = 200, Ec = 64;
constexpr int Mtot = Bc * Sc;
constexpr float DT = 0.25f;     // 1/N_EULER
constexpr int KP = 224;         // padded L/O dim (7*32)

enum { MODE_ENC = 0, MODE_QKV = 3, MODE_OUT = 4, MODE_BF16OUT = 5 };

typedef short bf16x8 __attribute__((ext_vector_type(8)));
typedef float f32x4 __attribute__((ext_vector_type(4)));
typedef unsigned short u16x8 __attribute__((ext_vector_type(8)));

__device__ inline unsigned short f2bf(float x) {
    union { float f; unsigned int u; } v; v.f = x;
    unsigned int r = v.u + 0x7FFFu + ((v.u >> 16) & 1u);   // RNE
    return (unsigned short)(r >> 16);
}
__device__ inline float bf2f(unsigned short x) {
    union { unsigned int u; float f; } v; v.u = ((unsigned int)x) << 16;
    return v.f;
}
__device__ inline float fast_tanh(float x) {
    float cx = fminf(fmaxf(x, -15.f), 15.f);
    float e = __expf(2.f * cx);
    return __fdividef(e - 1.f, e + 1.f);
}

// ---------------------------------------------------------------------------
__global__ __launch_bounds__(256) void eco_kernel(
    const float* __restrict__ eco_data, const float* __restrict__ W_eco,
    const float* __restrict__ b_eco, float* __restrict__ eco_vec)
{
    const int b = blockIdx.x, h = threadIdx.x;
    float acc = b_eco[h];
    #pragma unroll
    for (int e = 0; e < Ec; e++)
        acc = fmaf(eco_data[b * Ec + e], W_eco[(size_t)e * Hc + h], acc);
    eco_vec[(size_t)b * Hc + h] = acc;
}

// ---------------------------------------------------------------------------
// W fp32 [K][N] (z slices) -> WT bf16 [Npad][Kpad], zero-padded.
// ---------------------------------------------------------------------------
__global__ void wtrans_kernel(const float* __restrict__ W, unsigned short* __restrict__ WT,
                              int K, int N, int Kpad, int Npad)
{
    const int z = blockIdx.z;
    const int n = blockIdx.x * 16 + threadIdx.x;
    const int k = blockIdx.y * 16 + threadIdx.y;
    if (n >= Npad || k >= Kpad) return;
    float v = (n < N && k < K) ? W[(size_t)z * K * N + (size_t)k * N + n] : 0.f;
    WT[(size_t)z * Npad * Kpad + (size_t)n * Kpad + k] = f2bf(v);
}

// ---------------------------------------------------------------------------
// bf16 MFMA GEMM, 128x128 tile, 4 waves of 64x64, 16x16x32 MFMA.
// ---------------------------------------------------------------------------
template <int MODE, typename TA>
__global__ __launch_bounds__(256) void mfma_gemm(
    const TA* __restrict__ A, const unsigned short* __restrict__ WT,
    const float* __restrict__ bias, void* __restrict__ Cv,
    int M, int N, int K, int Kpad,
    size_t aStrideZ, size_t wStrideZ, size_t bStrideZ, size_t cStrideZ,
    const float* __restrict__ timev, const float* __restrict__ wtv,
    const float* __restrict__ eco, const float* __restrict__ trandat,
    unsigned short* __restrict__ Ck, unsigned short* __restrict__ Cvt)
{
    constexpr int LDS_S = 40;
    __shared__ unsigned short As[128 * LDS_S];
    __shared__ unsigned short Bs[128 * LDS_S];

    const int tid = threadIdx.x;
    const int z = blockIdx.z;
    const int m0 = blockIdx.y * 128;
    const int n0 = blockIdx.x * 128;

    A    += (size_t)z * aStrideZ;
    WT   += (size_t)z * wStrideZ;
    bias += (size_t)z * bStrideZ;
    float* Cf = (float*)Cv + (size_t)z * cStrideZ;
    unsigned short* Cu = (unsigned short*)Cv + (size_t)z * cStrideZ;
    const float* wtp = wtv ? (wtv + (size_t)z * Lc) : nullptr;

    const int lane = tid & 63, wave = tid >> 6;
    const int wm = (wave & 1) * 64, wn = (wave >> 1) * 64;
    const int fm = lane & 15, fq = lane >> 4;

    f32x4 acc[4][4];
    #pragma unroll
    for (int i = 0; i < 4; i++)
        #pragma unroll
        for (int j = 0; j < 4; j++)
            acc[i][j] = (f32x4){0.f, 0.f, 0.f, 0.f};

    for (int k0 = 0; k0 < K; k0 += 32) {
        if (k0) __syncthreads();
        #pragma unroll
        for (int i = 0; i < 4; i++) {
            const int f = i * 256 + tid;
            const int row = f >> 3, kq = f & 7;
            const int k = k0 + kq * 4;
            ushort4 s;
            if constexpr (sizeof(TA) == 4) {
                float4 v = {0.f, 0.f, 0.f, 0.f};
                if (k < K) v = *(const float4*)((const float*)A + (size_t)(m0 + row) * K + k);
                s.x = f2bf(v.x); s.y = f2bf(v.y); s.z = f2bf(v.z); s.w = f2bf(v.w);
            } else {
                s = make_ushort4(0, 0, 0, 0);
                if (k < K) s = *(const ushort4*)((const unsigned short*)A + (size_t)(m0 + row) * K + k);
            }
            *(ushort4*)&As[row * LDS_S + kq * 4] = s;
        }
        #pragma unroll
        for (int i = 0; i < 2; i++) {
            const int f = i * 256 + tid;
            const int row = f >> 2, q = f & 3;
            u16x8 v = *(const u16x8*)(WT + (size_t)(n0 + row) * Kpad + k0 + q * 8);
            *(u16x8*)&Bs[row * LDS_S + q * 8] = v;
        }
        __syncthreads();

        bf16x8 af[4], bfr[4];
        #pragma unroll
        for (int mi = 0; mi < 4; mi++)
            af[mi] = *(const bf16x8*)&As[(wm + mi * 16 + fm) * LDS_S + fq * 8];
        #pragma unroll
        for (int nj = 0; nj < 4; nj++)
            bfr[nj] = *(const bf16x8*)&Bs[(wn + nj * 16 + fm) * LDS_S + fq * 8];
        #pragma unroll
        for (int mi = 0; mi < 4; mi++)
            #pragma unroll
            for (int nj = 0; nj < 4; nj++)
                acc[mi][nj] = __builtin_amdgcn_mfma_f32_16x16x32_bf16(
                    af[mi], bfr[nj], acc[mi][nj], 0, 0, 0);
    }

    // epilogue: C/D layout col = lane&15, row = quad*4 + reg
    #pragma unroll
    for (int mi = 0; mi < 4; mi++) {
        #pragma unroll
        for (int nj = 0; nj < 4; nj++) {
            const int nn = n0 + wn + nj * 16 + fm;
            if (nn >= N) continue;
            const float bv = (MODE == MODE_BF16OUT) ? 0.f
                           : ((MODE == MODE_ENC && nn >= Lc) ? 0.f : bias[nn]);
            #pragma unroll
            for (int r = 0; r < 4; r++) {
                const int mm = m0 + wm + mi * 16 + fq * 4 + r;
                float v = acc[mi][nj][r] + bv;
                if (MODE == MODE_ENC) {
                    float vv = (nn < Lc) ? fast_tanh(v + timev[mm] * wtp[nn]) : 0.f;
                    Cu[(size_t)mm * N + nn] = f2bf(vv);
                } else if (MODE == MODE_QKV) {
                    v += eco[(size_t)(mm >> 10) * Hc + nn];
                    if (trandat[(size_t)mm * Hc + (Hc - 1)] == 0.f) v = 0.f;
                    const int bq = mm >> 10, sq = mm & (Sc - 1);
                    if (z == 0)      ((unsigned short*)Cv)[(size_t)mm * Hc + nn] = f2bf(v * 0.0625f);
                    else if (z == 1) Ck[(size_t)mm * Hc + nn] = f2bf(v);
                    else             Cvt[((size_t)bq * Hc + nn) * Sc + sq] = f2bf(v);
                } else if (MODE == MODE_BF16OUT) {
                    Cu[(size_t)mm * N + nn] = f2bf(v);
                } else {
                    Cf[(size_t)mm * N + nn] = v;
                }
            }
        }
    }
}

// ---------------------------------------------------------------------------
// Fused 4-iteration Euler solve, v2: 512 threads (8 waves), 128 rows/block,
// wave tile 32x112. Double-buffered W / hid-chunk LDS + one-chunk-ahead
// register prefetch -> 1 barrier per k-chunk; global W latency off the
// critical path. Dynamic LDS (113 KB).
// ---------------------------------------------------------------------------
__global__ __launch_bounds__(512, 2) void euler_fused(
    unsigned short* __restrict__ hg,       // [3][M][224] bf16, in/out
    const unsigned short* __restrict__ W1, // [3][256][224] bf16
    const unsigned short* __restrict__ W2, // [3][256][224] bf16
    const float* __restrict__ b1g, const float* __restrict__ b2g)
{
    constexpr int HS = 232;   // h LDS stride (u16)
    constexpr int WS = 40;    // W / hid chunk stride (u16)
    extern __shared__ unsigned short lds[];
    unsigned short* hs  = lds;                 // [128][232]  59,392 B
    unsigned short* wsb[2] = { lds + 29696, lds + 38656 };   // [224][40] each
    unsigned short* hcb[2] = { lds + 47616, lds + 52736 };   // [128][40] each

    const int tid = threadIdx.x;
    const int z = blockIdx.y;
    const int m0 = blockIdx.x * 128;
    unsigned short* hrow = hg + ((size_t)z * Mtot + m0) * KP;
    const unsigned short* W1z = W1 + (size_t)z * 256 * KP;
    const unsigned short* W2z = W2 + (size_t)z * 256 * KP;

    const int lane = tid & 63, w = tid >> 6;
    const int wm = (w & 3) * 32, wn = (w >> 2) * 112;
    const int fm = lane & 15, fq = lane >> 4;

    // staging geometry: 224 rows x 4 u16x8 per chunk = 896 vec-elems / 512 thr
    const int sr = tid >> 2, sq = tid & 3;
    const bool s2 = (tid < 384);

    // per-thread bias caches
    float b1r[7], b2r[7];
    #pragma unroll
    for (int nj = 0; nj < 7; nj++) {
        const int nn = wn + nj * 16 + fm;
        b1r[nj] = (nn < Oc) ? b1g[z * Oc + nn] : 0.f;
        b2r[nj] = (nn < Lc) ? b2g[z * Lc + nn] : 0.f;
    }

    // prefetch W1 chunk 0
    u16x8 pr0, pr1;
    pr0 = *(const u16x8*)&W1z[sr * KP + sq * 8];
    if (s2) pr1 = *(const u16x8*)&W1z[(sr + 128) * KP + sq * 8];

    // stage h tile: 128 x 224
    #pragma unroll
    for (int i = 0; i < 7; i++) {
        const int f = i * 512 + tid;
        const int r = f / 28, c = (f % 28) * 8;
        *(u16x8*)&hs[r * HS + c] = *(const u16x8*)&hrow[(size_t)r * KP + c];
    }

    for (int it = 0; it < 4; it++) {
        // ================= phase 1: hid = tanh(h @ W1 + b1) =================
        __syncthreads();                       // B0: hs/update visible, ws free
        *(u16x8*)&wsb[0][sr * WS + sq * 8] = pr0;
        if (s2) *(u16x8*)&wsb[0][(sr + 128) * WS + sq * 8] = pr1;
        pr0 = *(const u16x8*)&W1z[sr * KP + 32 + sq * 8];
        if (s2) pr1 = *(const u16x8*)&W1z[(sr + 128) * KP + 32 + sq * 8];
        __syncthreads();                       // B1: ws[0] ready

        f32x4 acc[2][7];
        #pragma unroll
        for (int mi = 0; mi < 2; mi++)
            #pragma unroll
            for (int nj = 0; nj < 7; nj++)
                acc[mi][nj] = (f32x4){0.f, 0.f, 0.f, 0.f};

        for (int k = 0; k < 7; k++) {
            if (k < 6) {
                unsigned short* wb = wsb[(k + 1) & 1];
                *(u16x8*)&wb[sr * WS + sq * 8] = pr0;
                if (s2) *(u16x8*)&wb[(sr + 128) * WS + sq * 8] = pr1;
                const unsigned short* src = (k + 2 < 7) ? (W1z + (k + 2) * 32) : W2z;
                pr0 = *(const u16x8*)&src[sr * KP + sq * 8];
                if (s2) pr1 = *(const u16x8*)&src[(sr + 128) * KP + sq * 8];
            }
            const unsigned short* wr = wsb[k & 1];
            bf16x8 af[2], bfr[7];
            #pragma unroll
            for (int mi = 0; mi < 2; mi++)
                af[mi] = *(const bf16x8*)&hs[(wm + mi * 16 + fm) * HS + k * 32 + fq * 8];
            #pragma unroll
            for (int nj = 0; nj < 7; nj++)
                bfr[nj] = *(const bf16x8*)&wr[(wn + nj * 16 + fm) * WS + fq * 8];
            #pragma unroll
            for (int mi = 0; mi < 2; mi++)
                #pragma unroll
                for (int nj = 0; nj < 7; nj++)
                    acc[mi][nj] = __builtin_amdgcn_mfma_f32_16x16x32_bf16(
                        af[mi], bfr[nj], acc[mi][nj], 0, 0, 0);
            __syncthreads();
        }

        // bias + tanh, pack (C layout: col = fm, row = fq*4+r)
        unsigned short hidp[2][7][4];
        #pragma unroll
        for (int mi = 0; mi < 2; mi++)
            #pragma unroll
            for (int nj = 0; nj < 7; nj++)
                #pragma unroll
                for (int r = 0; r < 4; r++)
                    hidp[mi][nj][r] = f2bf(fast_tanh(acc[mi][nj][r] + b1r[nj]));

        // ================= phase 2: h += DT * (hid @ W2 + b2) ===============
        // pr holds W2 chunk 0; last phase-1 barrier means ws free
        {
            *(u16x8*)&wsb[0][sr * WS + sq * 8] = pr0;
            if (s2) *(u16x8*)&wsb[0][(sr + 128) * WS + sq * 8] = pr1;
            pr0 = *(const u16x8*)&W2z[sr * KP + 32 + sq * 8];
            if (s2) pr1 = *(const u16x8*)&W2z[(sr + 128) * KP + 32 + sq * 8];
            // hid chunk 0 -> hc[0]
            #pragma unroll
            for (int t2 = 0; t2 < 2; t2++) {
                const int c0 = t2 * 16;
                if (c0 >= wn && c0 < wn + 112) {
                    const int nj = (c0 - wn) >> 4;
                    #pragma unroll
                    for (int mi = 0; mi < 2; mi++)
                        #pragma unroll
                        for (int r = 0; r < 4; r++)
                            hcb[0][(wm + mi * 16 + fq * 4 + r) * WS + t2 * 16 + fm] =
                                hidp[mi][nj][r];
                }
            }
        }
        __syncthreads();                       // ws[0]/hc[0] ready

        f32x4 fac[2][7];
        #pragma unroll
        for (int mi = 0; mi < 2; mi++)
            #pragma unroll
            for (int nj = 0; nj < 7; nj++)
                fac[mi][nj] = (f32x4){0.f, 0.f, 0.f, 0.f};

        for (int k = 0; k < 7; k++) {
            if (k < 6) {
                unsigned short* wb = wsb[(k + 1) & 1];
                unsigned short* hb = hcb[(k + 1) & 1];
                *(u16x8*)&wb[sr * WS + sq * 8] = pr0;
                if (s2) *(u16x8*)&wb[(sr + 128) * WS + sq * 8] = pr1;
                if (k + 2 < 7) {
                    pr0 = *(const u16x8*)&W2z[sr * KP + (k + 2) * 32 + sq * 8];
                    if (s2) pr1 = *(const u16x8*)&W2z[(sr + 128) * KP + (k + 2) * 32 + sq * 8];
                } else if (it != 3) {
                    pr0 = *(const u16x8*)&W1z[sr * KP + sq * 8];
                    if (s2) pr1 = *(const u16x8*)&W1z[(sr + 128) * KP + sq * 8];
                }
                // hid chunk k+1 -> hc[(k+1)&1]
                #pragma unroll
                for (int t2 = 0; t2 < 2; t2++) {
                    const int c0 = (k + 1) * 32 + t2 * 16;
                    if (c0 >= wn && c0 < wn + 112) {
                        const int nj = (c0 - wn) >> 4;
                        #pragma unroll
                        for (int mi = 0; mi < 2; mi++)
                            #pragma unroll
                            for (int r = 0; r < 4; r++)
                                hb[(wm + mi * 16 + fq * 4 + r) * WS + t2 * 16 + fm] =
                                    hidp[mi][nj][r];
                    }
                }
            }
            const unsigned short* wr = wsb[k & 1];
            const unsigned short* hr = hcb[k & 1];
            bf16x8 af2[2], bf2[7];
            #pragma unroll
            for (int mi = 0; mi < 2; mi++)
                af2[mi] = *(const bf16x8*)&hr[(wm + mi * 16 + fm) * WS + fq * 8];
            #pragma unroll
            for (int nj = 0; nj < 7; nj++)
                bf2[nj] = *(const bf16x8*)&wr[(wn + nj * 16 + fm) * WS + fq * 8];
            #pragma unroll
            for (int mi = 0; mi < 2; mi++)
                #pragma unroll
                for (int nj = 0; nj < 7; nj++)
                    fac[mi][nj] = __builtin_amdgcn_mfma_f32_16x16x32_bf16(
                        af2[mi], bf2[nj], fac[mi][nj], 0, 0, 0);
            __syncthreads();
        }

        // h update: rows wm..wm+32, cols wn..wn+112 (disjoint per wave)
        #pragma unroll
        for (int mi = 0; mi < 2; mi++)
            #pragma unroll
            for (int nj = 0; nj < 7; nj++) {
                const int nn = wn + nj * 16 + fm;
                #pragma unroll
                for (int r = 0; r < 4; r++) {
                    const int row = wm + mi * 16 + fq * 4 + r;
                    const float fv = fac[mi][nj][r] + b2r[nj];
                    hs[row * HS + nn] = f2bf(bf2f(hs[row * HS + nn]) + DT * fv);
                }
            }
        // next iteration's B0 barrier makes updates visible
    }

    __syncthreads();
    #pragma unroll
    for (int i = 0; i < 7; i++) {
        const int f = i * 512 + tid;
        const int r = f / 28, c = (f % 28) * 8;
        *(u16x8*)&hrow[(size_t)r * KP + c] = *(const u16x8*)&hs[r * HS + c];
    }
}

// ---------------------------------------------------------------------------
// Row softmax over P [32768][1024] bf16, in place. One wave per row.
// ---------------------------------------------------------------------------
__global__ __launch_bounds__(256) void softmax_kernel(unsigned short* __restrict__ P)
{
    const int row = blockIdx.x * 4 + (threadIdx.x >> 6);
    const int lane = threadIdx.x & 63;
    unsigned short* p = P + (size_t)row * Sc + lane * 16;
    const u16x8 a = *(const u16x8*)p;
    const u16x8 b = *(const u16x8*)(p + 8);
    float v[16];
    #pragma unroll
    for (int i = 0; i < 8; i++) { v[i] = bf2f(a[i]); v[8 + i] = bf2f(b[i]); }

    float mx = v[0];
    #pragma unroll
    for (int i = 1; i < 16; i++) mx = fmaxf(mx, v[i]);
    #pragma unroll
    for (int o = 32; o > 0; o >>= 1) mx = fmaxf(mx, __shfl_xor(mx, o, 64));

    float s = 0.f;
    #pragma unroll
    for (int i = 0; i < 16; i++) { v[i] = __expf(v[i] - mx); s += v[i]; }
    #pragma unroll
    for (int o = 32; o > 0; o >>= 1) s += __shfl_xor(s, o, 64);
    const float inv = 1.f / s;

    u16x8 oa, ob;
    #pragma unroll
    for (int i = 0; i < 8; i++) { oa[i] = f2bf(v[i] * inv); ob[i] = f2bf(v[8 + i] * inv); }
    *(u16x8*)p = oa;
    *(u16x8*)(p + 8) = ob;
}

// ---------------------------------------------------------------------------
extern "C" void kernel_launch(void* const* d_in, const int* in_sizes, int n_in,
                              void* d_out, int out_size, void* d_ws, size_t ws_size,
                              hipStream_t stream)
{
    const float* eco_data = (const float*)d_in[0];
    const float* tran     = (const float*)d_in[1];
    const float* time_x   = (const float*)d_in[3];
    const float* W_eco    = (const float*)d_in[6];
    const float* b_eco    = (const float*)d_in[7];
    const float* W_in     = (const float*)d_in[8];
    const float* W_t      = (const float*)d_in[9];
    const float* b_in     = (const float*)d_in[10];
    const float* W_f1     = (const float*)d_in[11];
    const float* b_f1     = (const float*)d_in[12];
    const float* W_f2     = (const float*)d_in[13];
    const float* b_f2     = (const float*)d_in[14];
    const float* W_out    = (const float*)d_in[15];
    const float* b_out    = (const float*)d_in[16];
    const float* W_lin    = (const float*)d_in[17];
    const float* b_lin    = (const float*)d_in[18];
    float* out = (float*)d_out;

    // Workspace: eco_vec f32 | hpad bf16[3][M][224] | Qb,Kb,VT bf16 | P bf16 | WT
    float* eco_vec = (float*)d_ws;                               // 8192 f
    unsigned short* hpad = (unsigned short*)(eco_vec + 8192);    // 22,020,096 u16
    unsigned short* Qb = hpad + (size_t)3 * Mtot * KP;
    unsigned short* Kb = Qb + (size_t)Mtot * Hc;
    unsigned short* VT = Kb + (size_t)Mtot * Hc;
    unsigned short* P  = VT + (size_t)Mtot * Hc;
    unsigned short* WinT  = P + (size_t)Mtot * Sc;
    unsigned short* Wf1T  = WinT  + (size_t)3 * 256 * 256;
    unsigned short* Wf2T  = Wf1T  + (size_t)3 * 256 * KP;
    unsigned short* WoutT = Wf2T  + (size_t)3 * 256 * KP;
    unsigned short* WlinT = WoutT + (size_t)3 * 256 * KP;
    unsigned short* ctxb = hpad;                                 // alias (h dead after qkv)

    // allow >64 KB dynamic LDS for euler_fused (host-side, idempotent)
    static_assert(128 * 232 + 2 * 224 * 40 + 2 * 128 * 40 == 57856, "lds layout");
    hipFuncSetAttribute((const void*)euler_fused,
                        hipFuncAttributeMaxDynamicSharedMemorySize, 57856 * 2);

    eco_kernel<<<Bc, Hc, 0, stream>>>(eco_data, W_eco, b_eco, eco_vec);

    const dim3 tb(16, 16);
    wtrans_kernel<<<dim3(16, 16, 3), tb, 0, stream>>>(W_in,  WinT,  256, 200, 256, 256);
    wtrans_kernel<<<dim3(16, 14, 3), tb, 0, stream>>>(W_f1,  Wf1T,  200, 200, 224, 256);
    wtrans_kernel<<<dim3(16, 14, 3), tb, 0, stream>>>(W_f2,  Wf2T,  200, 200, 224, 256);
    wtrans_kernel<<<dim3(16, 14, 3), tb, 0, stream>>>(W_out, WoutT, 200, 256, 224, 256);
    wtrans_kernel<<<dim3(8,  16, 1), tb, 0, stream>>>(W_lin, WlinT, 256,  96, 256, 128);

    const dim3 blk(256);

    // encode: hpad_k = tanh(tran @ W_in[k] + time_x*W_t[k] + b_in[k]), bf16 out
    mfma_gemm<MODE_ENC, float><<<dim3(2, 256, 3), blk, 0, stream>>>(
        tran, WinT, b_in, hpad, Mtot, KP, Hc, 256,
        0, 65536, Lc, (size_t)Mtot * KP, time_x, W_t, nullptr, nullptr, nullptr, nullptr);

    // fused 4-step Euler solve (128 rows/block, 8 waves, dbuf pipeline)
    euler_fused<<<dim3(Mtot / 128, 3), 512, 57856 * 2, stream>>>(
        hpad, Wf1T, Wf2T, b_f1, b_f2);

    // qkv: Q*scale, K, V^T written bf16
    mfma_gemm<MODE_QKV, unsigned short><<<dim3(2, 256, 3), blk, 0, stream>>>(
        hpad, WoutT, b_out, Qb, Mtot, Hc, KP, KP,
        (size_t)Mtot * KP, 57344, Hc, 0, nullptr, nullptr, eco_vec, tran, Kb, VT);

    // scores: P[b] = (Q*scale)[b] @ K[b]^T
    mfma_gemm<MODE_BF16OUT, unsigned short><<<dim3(8, 8, 32), blk, 0, stream>>>(
        Qb, Kb, nullptr, P, Sc, Sc, Hc, Hc,
        (size_t)Sc * Hc, (size_t)Sc * Hc, 0, (size_t)Sc * Sc,
        nullptr, nullptr, nullptr, nullptr, nullptr, nullptr);

    softmax_kernel<<<Mtot / 4, blk, 0, stream>>>(P);

    // ctx: ctx[b] = P[b] @ V[b]  (B operand = V^T)
    mfma_gemm<MODE_BF16OUT, unsigned short><<<dim3(2, 8, 32), blk, 0, stream>>>(
        P, VT, nullptr, ctxb, Sc, Hc, Sc, Sc,
        (size_t)Sc * Sc, (size_t)Hc * Sc, 0, (size_t)Sc * Hc,
        nullptr, nullptr, nullptr, nullptr, nullptr, nullptr);

    // out = ctx @ W_lin + b_lin
    mfma_gemm<MODE_OUT, unsigned short><<<dim3(1, 256, 1), blk, 0, stream>>>(
        ctxb, WlinT, b_lin, out, Mtot, Pc, Hc, 256,
        0, 0, 0, 0, nullptr, nullptr, nullptr, nullptr, nullptr, nullptr);
}